// Round 20
// baseline (247.864 us; speedup 1.0000x reference)
//
#include <hip/hip_runtime.h>
#include <hip/hip_bf16.h>
#include <math.h>

#define NTOK 4096
#define DIM  1024
#define HEADS 16
#define HD   64
#define CHUNK 1024
#define NCH 4
#define QBLK 128
#define NQT (NTOK / QBLK)          // 32
#define NITEMS (NQT * HEADS * NCH) // 2048

typedef __attribute__((ext_vector_type(8))) short bf16x8;
typedef __attribute__((ext_vector_type(4))) float f32x4;
typedef __attribute__((ext_vector_type(16))) float f32x16;

#define PLSWAP(a, b) asm volatile("v_permlane32_swap_b32 %0, %1" : "+v"(a), "+v"(b))
#define MAX3(a, b, c) fmaxf(fmaxf(a, b), c)

// ---- fused prologue: RMSNorm row + weight-slice f32->bf16 + seq_end/RoPE ----
// block `row` (grid NTOK): (a) RMSNorm of emb[row] -> xnb[row] (bf16);
// (b) convert 1024-elem slice (row>>2)*1024 of weight matrix (row&3);
// (c) thread 0 path: kv_end[row] binary search + RoPE sin/cos for n=row.
__global__ __launch_bounds__(256) void k_prologue(const float* __restrict__ emb,
                                                  const float* __restrict__ w,
                                                  const float* __restrict__ s0, const float* __restrict__ s1,
                                                  const float* __restrict__ s2, const float* __restrict__ s3,
                                                  const int* __restrict__ seq_ids, const int* __restrict__ gidx,
                                                  __hip_bfloat16* __restrict__ xn,
                                                  __hip_bfloat16* __restrict__ d0, __hip_bfloat16* __restrict__ d1,
                                                  __hip_bfloat16* __restrict__ d2, __hip_bfloat16* __restrict__ d3,
                                                  int* __restrict__ kv_end,
                                                  float* __restrict__ sin_t, float* __restrict__ cos_t) {
    int row = blockIdx.x;
    int t = threadIdx.x;

    // ---- (a) RMSNorm ----
    const float4* e4 = (const float4*)(emb + (size_t)row * DIM);
    float4 x = e4[t];
    float ss = x.x*x.x + x.y*x.y + x.z*x.z + x.w*x.w;
    #pragma unroll
    for (int off = 32; off > 0; off >>= 1) ss += __shfl_down(ss, off);
    __shared__ float red[4];
    int lane = t & 63, wid = t >> 6;
    if (lane == 0) red[wid] = ss;
    __syncthreads();
    float tot = red[0] + red[1] + red[2] + red[3];
    float scale = rsqrtf(tot * (1.0f / (float)DIM) + 1e-6f);
    float4 wv = ((const float4*)w)[t];
    union { __hip_bfloat16 h[4]; uint2 u; } pk;
    pk.h[0] = __float2bfloat16(x.x * scale * wv.x);
    pk.h[1] = __float2bfloat16(x.y * scale * wv.y);
    pk.h[2] = __float2bfloat16(x.z * scale * wv.z);
    pk.h[3] = __float2bfloat16(x.w * scale * wv.w);
    *(uint2*)(xn + (size_t)row * DIM + t * 4) = pk.u;

    // ---- (b) weight slice f32 -> bf16 (1024 elems of matrix row&3) ----
    {
        int z = row & 3;
        const float* s = (z == 0) ? s0 : (z == 1) ? s1 : (z == 2) ? s2 : s3;
        __hip_bfloat16* d = (z == 0) ? d0 : (z == 1) ? d1 : (z == 2) ? d2 : d3;
        size_t i = ((size_t)(row >> 2) * 1024) + (size_t)t * 4;
        float4 v = *(const float4*)(s + i);
        union { __hip_bfloat16 h[4]; uint2 u; } wk;
        wk.h[0] = __float2bfloat16(v.x);
        wk.h[1] = __float2bfloat16(v.y);
        wk.h[2] = __float2bfloat16(v.z);
        wk.h[3] = __float2bfloat16(v.w);
        *(uint2*)(d + i) = wk.u;
    }

    // ---- (c) seq_end + RoPE tables for n = row (32 lanes share the trig) ----
    if (t < 32) {
        int n = row;
        if (t == 0) {
            int id = seq_ids[n];
            int lo = n + 1, hi2 = NTOK;
            while (lo < hi2) {
                int mid = (lo + hi2) >> 1;
                if (seq_ids[mid] == id) lo = mid + 1; else hi2 = mid;
            }
            kv_end[n] = lo;  // union of causal and same-block == j < seq_end[n]
        }
        double pos = (double)gidx[n];
        const double lt = 13.122363377404328;  // log(500000)
        double ang = pos * exp(-(double)t * (1.0 / 32.0) * lt);
        sin_t[n * 32 + t] = (float)sin(ang);
        cos_t[n * 32 + t] = (float)cos(ang);
    }
}

// ---------------- shared MFMA GEMM core (128x128 tile, BK=32) ----------------
__device__ __forceinline__ void gemm_core(const __hip_bfloat16* __restrict__ A,
                                          const __hip_bfloat16* __restrict__ B,
                                          short* As, short* Bs,
                                          int bm, int bn, f32x4 (&acc)[4][4], int t) {
    int w = t >> 6, l = t & 63;
    int wm = w >> 1, wn = w & 1;
    int li = l & 15, lg = l >> 4;
    int lr = l >> 2, lc = l & 3;
    for (int kt = 0; kt < DIM; kt += 32) {
        #pragma unroll
        for (int i = 0; i < 2; i++) {
            int r = w * 32 + i * 16 + lr;
            int c = lc ^ ((r >> 1) & 3);
            const __hip_bfloat16* ga = A + (size_t)(bm * 128 + r) * DIM + kt + c * 8;
            __builtin_amdgcn_global_load_lds(
                (const __attribute__((address_space(1))) unsigned int*)ga,
                (__attribute__((address_space(3))) unsigned int*)(As + (w * 32 + i * 16) * 32),
                16, 0, 0);
            const __hip_bfloat16* gb = B + (size_t)(bn * 128 + r) * DIM + kt + c * 8;
            __builtin_amdgcn_global_load_lds(
                (const __attribute__((address_space(1))) unsigned int*)gb,
                (__attribute__((address_space(3))) unsigned int*)(Bs + (w * 32 + i * 16) * 32),
                16, 0, 0);
        }
        __syncthreads();
        bf16x8 af[4], bfr[4];
        #pragma unroll
        for (int mb = 0; mb < 4; mb++) {
            int r = wm * 64 + mb * 16 + li;
            af[mb] = *(const bf16x8*)((const char*)As + r * 64 + ((lg ^ ((r >> 1) & 3)) << 4));
        }
        #pragma unroll
        for (int nb = 0; nb < 4; nb++) {
            int r = wn * 64 + nb * 16 + li;
            bfr[nb] = *(const bf16x8*)((const char*)Bs + r * 64 + ((lg ^ ((r >> 1) & 3)) << 4));
        }
        #pragma unroll
        for (int mb = 0; mb < 4; mb++)
            #pragma unroll
            for (int nb = 0; nb < 4; nb++)
                acc[mb][nb] = __builtin_amdgcn_mfma_f32_16x16x32_bf16(af[mb], bfr[nb], acc[mb][nb], 0, 0, 0);
        __syncthreads();
    }
}

// ---------------- QKV projection + clip + RoPE (all MFMA) ----------------
__global__ __launch_bounds__(256) void k_qkv(const __hip_bfloat16* __restrict__ xn,
                                             const __hip_bfloat16* __restrict__ wq,
                                             const __hip_bfloat16* __restrict__ wk,
                                             const __hip_bfloat16* __restrict__ wv,
                                             const float* __restrict__ sin_t,
                                             const float* __restrict__ cos_t,
                                             __hip_bfloat16* __restrict__ qo,
                                             __hip_bfloat16* __restrict__ ko,
                                             __hip_bfloat16* __restrict__ vo) {
    __shared__ alignas(16) short As[128 * 32];
    __shared__ alignas(16) short Bs[128 * 32];
    int bm = blockIdx.x, bn = blockIdx.y, z = blockIdx.z;
    const __hip_bfloat16* W = (z == 0) ? wq : (z == 1) ? wk : wv;
    __hip_bfloat16* out = (z == 0) ? qo : (z == 1) ? ko : vo;
    int t = threadIdx.x;
    f32x4 acc[4][4] = {};
    gemm_core(xn, W, As, Bs, bm, bn, acc, t);

    int w = t >> 6, l = t & 63;
    int wm = w >> 1, wn = w & 1;
    int li = l & 15, lg = l >> 4;
    #pragma unroll
    for (int mb = 0; mb < 4; mb++)
        #pragma unroll
        for (int nb = 0; nb < 4; nb++)
            #pragma unroll
            for (int r = 0; r < 4; r++)
                acc[mb][nb][r] = fminf(fmaxf(acc[mb][nb][r], -8.0f), 8.0f);

    int h = bn * 2 + wn;   // wave owns one full head (64 cols)
    if (z < 2) {
        // RoPE in-register: partner d+-32 = fragment nb^2, same lane.
        #pragma unroll
        for (int mb = 0; mb < 4; mb++) {
            #pragma unroll
            for (int r = 0; r < 4; r++) {
                int n = bm * 128 + wm * 64 + mb * 16 + lg * 4 + r;
                float s0 = sin_t[n * 32 + li],      c0 = cos_t[n * 32 + li];
                float s1 = sin_t[n * 32 + 16 + li], c1 = cos_t[n * 32 + 16 + li];
                float v0 = acc[mb][0][r], v1 = acc[mb][1][r];
                float v2 = acc[mb][2][r], v3 = acc[mb][3][r];
                __hip_bfloat16* op = out + ((size_t)h * NTOK + n) * HD + li;
                op[0]  = __float2bfloat16(v0 * c0 - v2 * s0);
                op[16] = __float2bfloat16(v1 * c1 - v3 * s1);
                op[32] = __float2bfloat16(v2 * c0 + v0 * s0);
                op[48] = __float2bfloat16(v3 * c1 + v1 * s1);
            }
        }
    } else {
        #pragma unroll
        for (int mb = 0; mb < 4; mb++) {
            #pragma unroll
            for (int r = 0; r < 4; r++) {
                int n = bm * 128 + wm * 64 + mb * 16 + lg * 4 + r;
                __hip_bfloat16* op = out + ((size_t)h * NTOK + n) * HD + li;
                op[0]  = __float2bfloat16(acc[mb][0][r]);
                op[16] = __float2bfloat16(acc[mb][1][r]);
                op[32] = __float2bfloat16(acc[mb][2][r]);
                op[48] = __float2bfloat16(acc[mb][3][r]);
            }
        }
    }
}

// ---------------- output projection (MFMA), f32 out ----------------
__global__ __launch_bounds__(256) void k_wo(const __hip_bfloat16* __restrict__ ao,
                                            const __hip_bfloat16* __restrict__ wo,
                                            float* __restrict__ out) {
    __shared__ alignas(16) short As[128 * 32];
    __shared__ alignas(16) short Bs[128 * 32];
    int bm = blockIdx.x, bn = blockIdx.y;
    int t = threadIdx.x;
    f32x4 acc[4][4] = {};
    gemm_core(ao, wo, As, Bs, bm, bn, acc, t);

    int w = t >> 6, l = t & 63;
    int wm = w >> 1, wn = w & 1;
    int li = l & 15, lg = l >> 4;
    #pragma unroll
    for (int mb = 0; mb < 4; mb++) {
        #pragma unroll
        for (int r = 0; r < 4; r++) {
            int n = bm * 128 + wm * 64 + mb * 16 + lg * 4 + r;
            float* op = out + (size_t)n * DIM + bn * 128 + wn * 64 + li;
            op[0]  = acc[mb][0][r];
            op[16] = acc[mb][1][r];
            op[32] = acc[mb][2][r];
            op[48] = acc[mb][3][r];
        }
    }
}

// ---------------- split-K flash attention, 32x32 MFMA, q lane-local ----------
// One item per block, item = blockIdx.x (no atomics -> trivially deterministic).
// S^T = mfma32(K, Q): lane owns q = lane&31 for softmax AND O^T accumulation.
__global__ __launch_bounds__(256) void k_attn(const __hip_bfloat16* __restrict__ qg,
                                              const __hip_bfloat16* __restrict__ kg,
                                              const __hip_bfloat16* __restrict__ vg,
                                              const int* __restrict__ kv_end,
                                              float* __restrict__ opart,
                                              float* __restrict__ mlpart,
                                              __hip_bfloat16* __restrict__ ao) {
    int t = threadIdx.x;
    int w = t >> 6, lane = t & 63;
    int lq = lane & 31, hi = lane >> 5;

    __shared__ short Ks[64 * 64];   // [key][hd]   byte: key*128 + ((2d) ^ (key&7)<<4)
    __shared__ short Vt[64 * 64];   // [dim][key]  byte: d*128 + ((2k) ^ ((d&7)<<4 ^ ((d>>4)&3)<<5))
    char* KsB = (char*)Ks;
    char* VtB = (char*)Vt;

    int skey = t >> 2;            // staging: key row 0..63
    int sc0 = (t & 3) * 16;       // staging: 16-elem chunk
    const float SC = 0.18033688011112042f;           // 0.125 * log2(e)
    const float THR = 11.0f;                         // defer-max threshold (log2)

    int item = blockIdx.x;
    int qt = (NQT - 1) - (item >> 6);   // long q-tiles first
    int h = (item >> 2) & 15;
    int c = item & 3;

    int kmaxf = kv_end[qt * QBLK + QBLK - 1];   // ids sorted -> monotone bound
    int jstart = c * CHUNK;
    if (jstart >= kmaxf) return;
    int jend = min(jstart + CHUNK, kmaxf);
    int nch = (kmaxf + CHUNK - 1) / CHUNK;

    int qrow = qt * QBLK + w * 32 + lq;
    const __hip_bfloat16* qh = qg + ((size_t)h * NTOK + qrow) * HD;
    bf16x8 qa[4];
    #pragma unroll
    for (int s = 0; s < 4; s++)
        qa[s] = *(const bf16x8*)(qh + hi * 8 + s * 16);

    int ke = kv_end[qrow];                            // bound for q (lane-local)
    int ke0 = kv_end[qt * QBLK + w * 32];             // min bound in wave
    int wave_kemax = kv_end[qt * QBLK + w * 32 + 31]; // wave activity bound

    float m = -1e30f, l = 0.f;                        // lane-partial over hi halves
    f32x16 acc_ot[2] = {};                            // O^T: row d, col q=lq

    // prefetch first tile
    const __hip_bfloat16* kh = kg + ((size_t)h * NTOK + jstart + skey) * HD;
    const __hip_bfloat16* vh = vg + ((size_t)h * NTOK + jstart + skey) * HD;
    bf16x8 kr0 = *(const bf16x8*)(kh + sc0);
    bf16x8 kr1 = *(const bf16x8*)(kh + sc0 + 8);
    bf16x8 vr0 = *(const bf16x8*)(vh + sc0);
    bf16x8 vr1 = *(const bf16x8*)(vh + sc0 + 8);

    for (int jt = jstart; jt < jend; jt += 64) {
        // ---- stage regs -> LDS ----
        int kswz = (skey & 7) << 4;
        *(bf16x8*)(KsB + skey * 128 + ((sc0 * 2) ^ kswz)) = kr0;
        *(bf16x8*)(KsB + skey * 128 + ((sc0 * 2 + 16) ^ kswz)) = kr1;
        int vsega = (((sc0 >> 4) & 3) << 5);
        #pragma unroll
        for (int j = 0; j < 8; j++) {
            int r0 = sc0 + j, r1 = sc0 + 8 + j;
            *(short*)(VtB + r0 * 128 + ((skey * 2) ^ (((r0 & 7) << 4) ^ vsega))) = vr0[j];
            *(short*)(VtB + r1 * 128 + ((skey * 2) ^ (((r1 & 7) << 4) ^ vsega))) = vr1[j];
        }
        __syncthreads();

        // ---- prefetch next tile ----
        if (jt + 64 < jend) {
            const __hip_bfloat16* kh2 = kg + ((size_t)h * NTOK + jt + 64 + skey) * HD;
            const __hip_bfloat16* vh2 = vg + ((size_t)h * NTOK + jt + 64 + skey) * HD;
            kr0 = *(const bf16x8*)(kh2 + sc0);
            kr1 = *(const bf16x8*)(kh2 + sc0 + 8);
            vr0 = *(const bf16x8*)(vh2 + sc0);
            vr1 = *(const bf16x8*)(vh2 + sc0 + 8);
        }

        if (wave_kemax > jt) {   // wave-uniform: skip fully-masked waves
            // ---- S^T = K Q^T : two 32x32 blocks (keys kb*32..+31) ----
            f32x16 sacc[2] = {};
            __builtin_amdgcn_s_setprio(1);
            #pragma unroll
            for (int kb = 0; kb < 2; kb++) {
                int key = lq + 32 * kb;
                int ksw = (key & 7) << 4;
                #pragma unroll
                for (int s = 0; s < 4; s++) {
                    bf16x8 kf = *(const bf16x8*)(KsB + key * 128 + ((hi * 16 + 32 * s) ^ ksw));
                    sacc[kb] = __builtin_amdgcn_mfma_f32_32x32x16_bf16(kf, qa[s], sacc[kb], 0, 0, 0);
                }
            }
            __builtin_amdgcn_s_setprio(0);

            // ---- mask RAW scores in place (boundary tiles only) ----
            if (jt + 64 > ke0) {
                #pragma unroll
                for (int kb = 0; kb < 2; kb++)
                    #pragma unroll
                    for (int r = 0; r < 16; r++) {
                        int j = jt + 32 * kb + (r & 3) + 8 * (r >> 2) + 4 * hi;
                        if (j >= ke) sacc[kb][r] = -1e30f;
                    }
            }

            // ---- max via max3 tree on raw scores; single scale ----
            float a0  = MAX3(sacc[0][0],  sacc[0][1],  sacc[0][2]);
            float a1  = MAX3(sacc[0][3],  sacc[0][4],  sacc[0][5]);
            float a2  = MAX3(sacc[0][6],  sacc[0][7],  sacc[0][8]);
            float a3  = MAX3(sacc[0][9],  sacc[0][10], sacc[0][11]);
            float a4  = MAX3(sacc[0][12], sacc[0][13], sacc[0][14]);
            float a5  = MAX3(sacc[0][15], sacc[1][0],  sacc[1][1]);
            float a6  = MAX3(sacc[1][2],  sacc[1][3],  sacc[1][4]);
            float a7  = MAX3(sacc[1][5],  sacc[1][6],  sacc[1][7]);
            float a8  = MAX3(sacc[1][8],  sacc[1][9],  sacc[1][10]);
            float a9  = MAX3(sacc[1][11], sacc[1][12], sacc[1][13]);
            float a10 = fmaxf(sacc[1][14], sacc[1][15]);
            float b0 = MAX3(a0, a1, a2);
            float b1 = MAX3(a3, a4, a5);
            float b2 = MAX3(a6, a7, a8);
            float b3 = MAX3(a9, a10, b0);
            float mx = MAX3(b1, b2, b3) * SC;
            mx = fmaxf(mx, __shfl_xor(mx, 32));
            // Clamp: valid scores give mx >= -739; all-masked lanes get -1e9
            // so mn can never equal the sentinel*SC (no fma-residual inf).
            mx = fmaxf(mx, -1e9f);

            float p[2][16];
            if (__all(mx <= m + THR)) {
                // defer-max: keep old m; exp2(fma(raw, SC, -m))
                float nm = -m;
                float l0 = 0.f, l1 = 0.f, l2 = 0.f, l3 = 0.f;
                #pragma unroll
                for (int kb = 0; kb < 2; kb++)
                    #pragma unroll
                    for (int r = 0; r < 16; r++) {
                        float e = exp2f(fmaf(sacc[kb][r], SC, nm));
                        p[kb][r] = e;
                        if ((r & 3) == 0) l0 += e;
                        else if ((r & 3) == 1) l1 += e;
                        else if ((r & 3) == 2) l2 += e;
                        else l3 += e;
                    }
                l += (l0 + l1) + (l2 + l3);
            } else {
                float mn = fmaxf(m, mx);
                float al = exp2f(m - mn);
                l *= al;
                float nm = -mn;
                float l0 = 0.f, l1 = 0.f, l2 = 0.f, l3 = 0.f;
                #pragma unroll
                for (int kb = 0; kb < 2; kb++)
                    #pragma unroll
                    for (int r = 0; r < 16; r++) {
                        float e = exp2f(fmaf(sacc[kb][r], SC, nm));
                        p[kb][r] = e;
                        if ((r & 3) == 0) l0 += e;
                        else if ((r & 3) == 1) l1 += e;
                        else if ((r & 3) == 2) l2 += e;
                        else l3 += e;
                    }
                l += (l0 + l1) + (l2 + l3);
                m = mn;
                #pragma unroll
                for (int db = 0; db < 2; db++)
                    #pragma unroll
                    for (int r = 0; r < 16; r++) acc_ot[db][r] *= al;   // al lane-local (q=lq)
            }

            // ---- pack P pairs; permlane32_swap -> PV B-frags in place ----
            uint pw[2][8];
            #pragma unroll
            for (int kb = 0; kb < 2; kb++)
                #pragma unroll
                for (int i = 0; i < 8; i++) {
                    union { __hip_bfloat16 b[2]; uint u; } cv;
                    cv.b[0] = __float2bfloat16(p[kb][2 * i]);
                    cv.b[1] = __float2bfloat16(p[kb][2 * i + 1]);
                    pw[kb][i] = cv.u;
                }
            #pragma unroll
            for (int kb = 0; kb < 2; kb++) {
                PLSWAP(pw[kb][0], pw[kb][2]);
                PLSWAP(pw[kb][1], pw[kb][3]);
                PLSWAP(pw[kb][4], pw[kb][6]);
                PLSWAP(pw[kb][5], pw[kb][7]);
            }

            // ---- O^T += V^T P^T : D[d][q], col q = lq ----
            __builtin_amdgcn_s_setprio(1);
            #pragma unroll
            for (int db = 0; db < 2; db++) {
                int d = lq + 32 * db;
                int vsw = ((d & 7) << 4) ^ (((d >> 4) & 3) << 5);
                #pragma unroll
                for (int kb = 0; kb < 2; kb++)
                    #pragma unroll
                    for (int s = 0; s < 2; s++) {
                        bf16x8 vf = *(const bf16x8*)(VtB + d * 128 + ((hi * 16 + 32 * s + 64 * kb) ^ vsw));
                        union { uint u[4]; bf16x8 v; } pf;
                        pf.u[0] = pw[kb][4 * s + 0];
                        pf.u[1] = pw[kb][4 * s + 1];
                        pf.u[2] = pw[kb][4 * s + 2];
                        pf.u[3] = pw[kb][4 * s + 3];
                        acc_ot[db] = __builtin_amdgcn_mfma_f32_32x32x16_bf16(vf, pf.v, acc_ot[db], 0, 0, 0);
                    }
            }
            __builtin_amdgcn_s_setprio(0);
        }
        __syncthreads();
    }

    // reduce lane-partial l across hi halves (q = lq both)
    l += __shfl_xor(l, 32);

    if (nch == 1) {
        float lr = 1.0f / l;   // lane-local
        #pragma unroll
        for (int db = 0; db < 2; db++)
            #pragma unroll
            for (int i = 0; i < 8; i++) {
                int dl = (2 * i & 3) + 8 * ((2 * i) >> 2) + 4 * hi;   // d_local of reg 2i
                union { __hip_bfloat16 b[2]; uint u; } cv;
                cv.b[0] = __float2bfloat16(acc_ot[db][2 * i] * lr);
                cv.b[1] = __float2bfloat16(acc_ot[db][2 * i + 1] * lr);
                *(uint*)(ao + (size_t)qrow * DIM + h * 64 + db * 32 + dl) = cv.u;
            }
    } else {
        // opart layout [item][d=64][q=128]: coalesced (q contiguous per d)
        size_t ob = ((size_t)(c * NQT + qt) * HEADS + h) * (64 * QBLK);
        int qloc = w * 32 + lq;
        #pragma unroll
        for (int db = 0; db < 2; db++)
            #pragma unroll
            for (int r = 0; r < 16; r++) {
                int dl = (r & 3) + 8 * (r >> 2) + 4 * hi + 32 * db;
                opart[ob + (size_t)dl * QBLK + qloc] = acc_ot[db][r];
            }
        if (hi == 0) {
            size_t mb = ((size_t)(c * NQT + qt) * HEADS + h) * (2 * QBLK);
            mlpart[mb + qloc] = m;
            mlpart[mb + QBLK + qloc] = l;
        }
    }
}

// ---------------- merge split-K partials (opart [d][q]; LDS-transposed writes) ----
__global__ __launch_bounds__(256) void k_merge(const int* __restrict__ kv_end,
                                               const float* __restrict__ opart,
                                               const float* __restrict__ mlpart,
                                               __hip_bfloat16* __restrict__ ao) {
    int qt = blockIdx.x, h = blockIdx.y;
    int kmaxf = kv_end[qt * QBLK + QBLK - 1];
    int nch = (kmaxf + CHUNK - 1) / CHUNK;
    if (nch == 1) return;                    // k_attn wrote ao directly
    __shared__ float os[64][QBLK + 4];       // [d][q], +4 pad
    int t = threadIdx.x;
    int qq = (t & 31) * 4;                   // 4 consecutive q (phase 1)
    int dsub = t >> 5;                       // 0..7

    // per-q merge weights for qq..qq+3
    float4 wc4[NCH];
    float4 inv4;
    {
        float4 mc[NCH], lc[NCH];
        float4 mstar = {-1e30f, -1e30f, -1e30f, -1e30f};
        for (int c = 0; c < nch; c++) {
            size_t mb = ((size_t)(c * NQT + qt) * HEADS + h) * (2 * QBLK);
            mc[c] = *(const float4*)(mlpart + mb + qq);
            lc[c] = *(const float4*)(mlpart + mb + QBLK + qq);
            mstar.x = fmaxf(mstar.x, mc[c].x); mstar.y = fmaxf(mstar.y, mc[c].y);
            mstar.z = fmaxf(mstar.z, mc[c].z); mstar.w = fmaxf(mstar.w, mc[c].w);
        }
        float4 lsum = {0.f, 0.f, 0.f, 0.f};
        for (int c = 0; c < nch; c++) {
            wc4[c].x = exp2f(mc[c].x - mstar.x); wc4[c].y = exp2f(mc[c].y - mstar.y);
            wc4[c].z = exp2f(mc[c].z - mstar.z); wc4[c].w = exp2f(mc[c].w - mstar.w);
            lsum.x += lc[c].x * wc4[c].x; lsum.y += lc[c].y * wc4[c].y;
            lsum.z += lc[c].z * wc4[c].z; lsum.w += lc[c].w * wc4[c].w;
        }
        inv4.x = 1.0f / lsum.x; inv4.y = 1.0f / lsum.y;
        inv4.z = 1.0f / lsum.z; inv4.w = 1.0f / lsum.w;
    }

    // phase 1: coalesced opart reads -> weighted sum -> LDS [d][q]
    #pragma unroll
    for (int iter = 0; iter < 8; iter++) {
        int d = iter * 8 + dsub;
        float4 acc = {0.f, 0.f, 0.f, 0.f};
        for (int c = 0; c < nch; c++) {
            const float4 v = *(const float4*)(opart +
                ((size_t)(c * NQT + qt) * HEADS + h) * (64 * QBLK) + (size_t)d * QBLK + qq);
            acc.x += v.x * wc4[c].x; acc.y += v.y * wc4[c].y;
            acc.z += v.z * wc4[c].z; acc.w += v.w * wc4[c].w;
        }
        acc.x *= inv4.x; acc.y *= inv4.y; acc.z *= inv4.z; acc.w *= inv4.w;
        os[d][qq + 0] = acc.x; os[d][qq + 1] = acc.y;
        os[d][qq + 2] = acc.z; os[d][qq + 3] = acc.w;
    }
    __syncthreads();

    // phase 2: transpose out of LDS; 64B contiguous global write per thread
    int q = t >> 1, d0 = (t & 1) * 32;
    uint buf[16];
    #pragma unroll
    for (int j = 0; j < 16; j++) {
        union { __hip_bfloat16 b[2]; uint u; } cv;
        cv.b[0] = __float2bfloat16(os[d0 + 2 * j][q]);
        cv.b[1] = __float2bfloat16(os[d0 + 2 * j + 1][q]);
        buf[j] = cv.u;
    }
    uint4* dst = (uint4*)(ao + (size_t)(qt * QBLK + q) * DIM + h * 64 + d0);
    dst[0] = make_uint4(buf[0], buf[1], buf[2], buf[3]);
    dst[1] = make_uint4(buf[4], buf[5], buf[6], buf[7]);
    dst[2] = make_uint4(buf[8], buf[9], buf[10], buf[11]);
    dst[3] = make_uint4(buf[12], buf[13], buf[14], buf[15]);
}

extern "C" void kernel_launch(void* const* d_in, const int* in_sizes, int n_in,
                              void* d_out, int out_size, void* d_ws, size_t ws_size,
                              hipStream_t stream) {
    const float* emb   = (const float*)d_in[0];
    const float* normw = (const float*)d_in[1];
    const float* Wq    = (const float*)d_in[2];
    const float* Wk    = (const float*)d_in[3];
    const float* Wv    = (const float*)d_in[4];
    const float* Wo    = (const float*)d_in[5];
    const int*   gidx  = (const int*)d_in[7];
    const int*   sids  = (const int*)d_in[8];
    float* out = (float*)d_out;

    const size_t M4 = (size_t)NTOK * DIM;
    const size_t M1 = (size_t)DIM * DIM;
    __hip_bfloat16* xnb = (__hip_bfloat16*)d_ws;             // 4M
    __hip_bfloat16* wqb = xnb + M4;                          // 1M x4
    __hip_bfloat16* wkb = wqb + M1;
    __hip_bfloat16* wvb = wkb + M1;
    __hip_bfloat16* wob = wvb + M1;
    __hip_bfloat16* qb  = wob + M1;                          // 4M x3
    __hip_bfloat16* kb  = qb + M4;
    __hip_bfloat16* vb  = kb + M4;
    __hip_bfloat16* aob = vb + M4;                           // 4M
    float* sint = (float*)(aob + M4);                        // [4096][32]
    float* cost = sint + (size_t)NTOK * 32;
    int*   kvend = (int*)(cost + (size_t)NTOK * 32);         // [4096]
    float* opart = (float*)(kvend + NTOK);                   // [4][32][16][64*128] f32 = 64MB
    float* mlpart = opart + (size_t)NCH * NQT * HEADS * (64 * QBLK);  // [4][32][16][2*128] f32

    hipLaunchKernelGGL(k_prologue, dim3(NTOK), dim3(256), 0, stream,
                       emb, normw, Wq, Wk, Wv, Wo, sids, gidx,
                       xnb, wqb, wkb, wvb, wob, kvend, sint, cost);
    hipLaunchKernelGGL(k_qkv, dim3(NTOK / 128, DIM / 128, 3), dim3(256), 0, stream,
                       xnb, wqb, wkb, wvb, sint, cost, qb, kb, vb);
    hipLaunchKernelGGL(k_attn, dim3(NITEMS), dim3(256), 0, stream,
                       qb, kb, vb, kvend, opart, mlpart, aob);
    hipLaunchKernelGGL(k_merge, dim3(NQT, HEADS), dim3(256), 0, stream,
                       kvend, opart, mlpart, aob);
    hipLaunchKernelGGL(k_wo, dim3(NTOK / 128, DIM / 128), dim3(256), 0, stream,
                       aob, wob, out);
}

// Round 21
// 212.278 us; speedup vs baseline: 1.1676x; 1.1676x over previous
//
#include <hip/hip_runtime.h>
#include <hip/hip_bf16.h>
#include <math.h>

#define NTOK 4096
#define DIM  1024
#define HEADS 16
#define HD   64
#define CHUNK 1024
#define NCH 4
#define QBLK 128
#define NQT (NTOK / QBLK)          // 32
#define NITEMS (NQT * HEADS * NCH) // 2048

typedef __attribute__((ext_vector_type(8))) short bf16x8;
typedef __attribute__((ext_vector_type(4))) float f32x4;
typedef __attribute__((ext_vector_type(16))) float f32x16;

#define PLSWAP(a, b) asm volatile("v_permlane32_swap_b32 %0, %1" : "+v"(a), "+v"(b))
#define MAX3(a, b, c) fmaxf(fmaxf(a, b), c)

// ---- fused prologue: RMSNorm row + weight-slice f32->bf16 + seq_end/RoPE ----
// block `row` (grid NTOK): (a) RMSNorm of emb[row] -> xnb[row] (bf16);
// (b) convert 1024-elem slice (row>>2)*1024 of weight matrix (row&3);
// (c) lanes 0..31: kv_end[row] + RoPE sin/cos for n=row; row 0 resets ctr.
__global__ __launch_bounds__(256) void k_prologue(const float* __restrict__ emb,
                                                  const float* __restrict__ w,
                                                  const float* __restrict__ s0, const float* __restrict__ s1,
                                                  const float* __restrict__ s2, const float* __restrict__ s3,
                                                  const int* __restrict__ seq_ids, const int* __restrict__ gidx,
                                                  __hip_bfloat16* __restrict__ xn,
                                                  __hip_bfloat16* __restrict__ d0, __hip_bfloat16* __restrict__ d1,
                                                  __hip_bfloat16* __restrict__ d2, __hip_bfloat16* __restrict__ d3,
                                                  int* __restrict__ kv_end,
                                                  float* __restrict__ sin_t, float* __restrict__ cos_t,
                                                  int* __restrict__ ctr) {
    int row = blockIdx.x;
    int t = threadIdx.x;
    if (row == 0 && t == 0) ctr[0] = 0;   // reset attn work queue (stream-ordered)

    // ---- (a) RMSNorm ----
    const float4* e4 = (const float4*)(emb + (size_t)row * DIM);
    float4 x = e4[t];
    float ss = x.x*x.x + x.y*x.y + x.z*x.z + x.w*x.w;
    #pragma unroll
    for (int off = 32; off > 0; off >>= 1) ss += __shfl_down(ss, off);
    __shared__ float red[4];
    int lane = t & 63, wid = t >> 6;
    if (lane == 0) red[wid] = ss;
    __syncthreads();
    float tot = red[0] + red[1] + red[2] + red[3];
    float scale = rsqrtf(tot * (1.0f / (float)DIM) + 1e-6f);
    float4 wv = ((const float4*)w)[t];
    union { __hip_bfloat16 h[4]; uint2 u; } pk;
    pk.h[0] = __float2bfloat16(x.x * scale * wv.x);
    pk.h[1] = __float2bfloat16(x.y * scale * wv.y);
    pk.h[2] = __float2bfloat16(x.z * scale * wv.z);
    pk.h[3] = __float2bfloat16(x.w * scale * wv.w);
    *(uint2*)(xn + (size_t)row * DIM + t * 4) = pk.u;

    // ---- (b) weight slice f32 -> bf16 (1024 elems of matrix row&3) ----
    {
        int z = row & 3;
        const float* s = (z == 0) ? s0 : (z == 1) ? s1 : (z == 2) ? s2 : s3;
        __hip_bfloat16* d = (z == 0) ? d0 : (z == 1) ? d1 : (z == 2) ? d2 : d3;
        size_t i = ((size_t)(row >> 2) * 1024) + (size_t)t * 4;
        float4 v = *(const float4*)(s + i);
        union { __hip_bfloat16 h[4]; uint2 u; } wk;
        wk.h[0] = __float2bfloat16(v.x);
        wk.h[1] = __float2bfloat16(v.y);
        wk.h[2] = __float2bfloat16(v.z);
        wk.h[3] = __float2bfloat16(v.w);
        *(uint2*)(d + i) = wk.u;
    }

    // ---- (c) seq_end + RoPE tables for n = row ----
    if (t < 32) {
        int n = row;
        if (t == 0) {
            int id = seq_ids[n];
            int lo = n + 1, hi2 = NTOK;
            while (lo < hi2) {
                int mid = (lo + hi2) >> 1;
                if (seq_ids[mid] == id) lo = mid + 1; else hi2 = mid;
            }
            kv_end[n] = lo;  // union of causal and same-block == j < seq_end[n]
        }
        double pos = (double)gidx[n];
        const double lt = 13.122363377404328;  // log(500000)
        double ang = pos * exp(-(double)t * (1.0 / 32.0) * lt);
        sin_t[n * 32 + t] = (float)sin(ang);
        cos_t[n * 32 + t] = (float)cos(ang);
    }
}

// ---------------- shared MFMA GEMM core (128x128 tile, BK=32) ----------------
__device__ __forceinline__ void gemm_core(const __hip_bfloat16* __restrict__ A,
                                          const __hip_bfloat16* __restrict__ B,
                                          short* As, short* Bs,
                                          int bm, int bn, f32x4 (&acc)[4][4], int t) {
    int w = t >> 6, l = t & 63;
    int wm = w >> 1, wn = w & 1;
    int li = l & 15, lg = l >> 4;
    int lr = l >> 2, lc = l & 3;
    for (int kt = 0; kt < DIM; kt += 32) {
        #pragma unroll
        for (int i = 0; i < 2; i++) {
            int r = w * 32 + i * 16 + lr;
            int c = lc ^ ((r >> 1) & 3);
            const __hip_bfloat16* ga = A + (size_t)(bm * 128 + r) * DIM + kt + c * 8;
            __builtin_amdgcn_global_load_lds(
                (const __attribute__((address_space(1))) unsigned int*)ga,
                (__attribute__((address_space(3))) unsigned int*)(As + (w * 32 + i * 16) * 32),
                16, 0, 0);
            const __hip_bfloat16* gb = B + (size_t)(bn * 128 + r) * DIM + kt + c * 8;
            __builtin_amdgcn_global_load_lds(
                (const __attribute__((address_space(1))) unsigned int*)gb,
                (__attribute__((address_space(3))) unsigned int*)(Bs + (w * 32 + i * 16) * 32),
                16, 0, 0);
        }
        __syncthreads();
        bf16x8 af[4], bfr[4];
        #pragma unroll
        for (int mb = 0; mb < 4; mb++) {
            int r = wm * 64 + mb * 16 + li;
            af[mb] = *(const bf16x8*)((const char*)As + r * 64 + ((lg ^ ((r >> 1) & 3)) << 4));
        }
        #pragma unroll
        for (int nb = 0; nb < 4; nb++) {
            int r = wn * 64 + nb * 16 + li;
            bfr[nb] = *(const bf16x8*)((const char*)Bs + r * 64 + ((lg ^ ((r >> 1) & 3)) << 4));
        }
        #pragma unroll
        for (int mb = 0; mb < 4; mb++)
            #pragma unroll
            for (int nb = 0; nb < 4; nb++)
                acc[mb][nb] = __builtin_amdgcn_mfma_f32_16x16x32_bf16(af[mb], bfr[nb], acc[mb][nb], 0, 0, 0);
        __syncthreads();
    }
}

// ---------------- QKV projection + clip + RoPE (all MFMA) ----------------
__global__ __launch_bounds__(256) void k_qkv(const __hip_bfloat16* __restrict__ xn,
                                             const __hip_bfloat16* __restrict__ wq,
                                             const __hip_bfloat16* __restrict__ wk,
                                             const __hip_bfloat16* __restrict__ wv,
                                             const float* __restrict__ sin_t,
                                             const float* __restrict__ cos_t,
                                             __hip_bfloat16* __restrict__ qo,
                                             __hip_bfloat16* __restrict__ ko,
                                             __hip_bfloat16* __restrict__ vo) {
    __shared__ alignas(16) short As[128 * 32];
    __shared__ alignas(16) short Bs[128 * 32];
    int bm = blockIdx.x, bn = blockIdx.y, z = blockIdx.z;
    const __hip_bfloat16* W = (z == 0) ? wq : (z == 1) ? wk : wv;
    __hip_bfloat16* out = (z == 0) ? qo : (z == 1) ? ko : vo;
    int t = threadIdx.x;
    f32x4 acc[4][4] = {};
    gemm_core(xn, W, As, Bs, bm, bn, acc, t);

    int w = t >> 6, l = t & 63;
    int wm = w >> 1, wn = w & 1;
    int li = l & 15, lg = l >> 4;
    #pragma unroll
    for (int mb = 0; mb < 4; mb++)
        #pragma unroll
        for (int nb = 0; nb < 4; nb++)
            #pragma unroll
            for (int r = 0; r < 4; r++)
                acc[mb][nb][r] = fminf(fmaxf(acc[mb][nb][r], -8.0f), 8.0f);

    int h = bn * 2 + wn;   // wave owns one full head (64 cols)
    if (z < 2) {
        // RoPE in-register: partner d+-32 = fragment nb^2, same lane.
        #pragma unroll
        for (int mb = 0; mb < 4; mb++) {
            #pragma unroll
            for (int r = 0; r < 4; r++) {
                int n = bm * 128 + wm * 64 + mb * 16 + lg * 4 + r;
                float s0 = sin_t[n * 32 + li],      c0 = cos_t[n * 32 + li];
                float s1 = sin_t[n * 32 + 16 + li], c1 = cos_t[n * 32 + 16 + li];
                float v0 = acc[mb][0][r], v1 = acc[mb][1][r];
                float v2 = acc[mb][2][r], v3 = acc[mb][3][r];
                __hip_bfloat16* op = out + ((size_t)h * NTOK + n) * HD + li;
                op[0]  = __float2bfloat16(v0 * c0 - v2 * s0);
                op[16] = __float2bfloat16(v1 * c1 - v3 * s1);
                op[32] = __float2bfloat16(v2 * c0 + v0 * s0);
                op[48] = __float2bfloat16(v3 * c1 + v1 * s1);
            }
        }
    } else {
        #pragma unroll
        for (int mb = 0; mb < 4; mb++) {
            #pragma unroll
            for (int r = 0; r < 4; r++) {
                int n = bm * 128 + wm * 64 + mb * 16 + lg * 4 + r;
                __hip_bfloat16* op = out + ((size_t)h * NTOK + n) * HD + li;
                op[0]  = __float2bfloat16(acc[mb][0][r]);
                op[16] = __float2bfloat16(acc[mb][1][r]);
                op[32] = __float2bfloat16(acc[mb][2][r]);
                op[48] = __float2bfloat16(acc[mb][3][r]);
            }
        }
    }
}

// ---------------- output projection (MFMA), f32 out ----------------
__global__ __launch_bounds__(256) void k_wo(const __hip_bfloat16* __restrict__ ao,
                                            const __hip_bfloat16* __restrict__ wo,
                                            float* __restrict__ out) {
    __shared__ alignas(16) short As[128 * 32];
    __shared__ alignas(16) short Bs[128 * 32];
    int bm = blockIdx.x, bn = blockIdx.y;
    int t = threadIdx.x;
    f32x4 acc[4][4] = {};
    gemm_core(ao, wo, As, Bs, bm, bn, acc, t);

    int w = t >> 6, l = t & 63;
    int wm = w >> 1, wn = w & 1;
    int li = l & 15, lg = l >> 4;
    #pragma unroll
    for (int mb = 0; mb < 4; mb++) {
        #pragma unroll
        for (int r = 0; r < 4; r++) {
            int n = bm * 128 + wm * 64 + mb * 16 + lg * 4 + r;
            float* op = out + (size_t)n * DIM + bn * 128 + wn * 64 + li;
            op[0]  = acc[mb][0][r];
            op[16] = acc[mb][1][r];
            op[32] = acc[mb][2][r];
            op[48] = acc[mb][3][r];
        }
    }
}

// ---------------- persistent split-K flash attention, 32x32 MFMA, q lane-local ----
// One item per block (grid == NITEMS): any queue pop order computes identical
// results -> deterministic across graph replays. The completion-ordered pop
// schedules long items first (SRPT-like) -- measurably better than static
// item=blockIdx.x (R20: +41us). Softmax: max3 tree on RAW scores,
// exp via exp2(fma(s, SC, -m)); mx clamped >= -1e9 (sentinel safety).
__global__ __launch_bounds__(256) void k_attn(const __hip_bfloat16* __restrict__ qg,
                                              const __hip_bfloat16* __restrict__ kg,
                                              const __hip_bfloat16* __restrict__ vg,
                                              const int* __restrict__ kv_end,
                                              int* __restrict__ ctr,
                                              float* __restrict__ opart,
                                              float* __restrict__ mlpart,
                                              __hip_bfloat16* __restrict__ ao) {
    int t = threadIdx.x;
    int w = t >> 6, lane = t & 63;
    int lq = lane & 31, hi = lane >> 5;

    __shared__ short Ks[64 * 64];   // [key][hd]   byte: key*128 + ((2d) ^ (key&7)<<4)
    __shared__ short Vt[64 * 64];   // [dim][key]  byte: d*128 + ((2k) ^ ((d&7)<<4 ^ ((d>>4)&3)<<5))
    __shared__ int s_item;
    char* KsB = (char*)Ks;
    char* VtB = (char*)Vt;

    int skey = t >> 2;            // staging: key row 0..63
    int sc0 = (t & 3) * 16;       // staging: 16-elem chunk
    const float SC = 0.18033688011112042f;           // 0.125 * log2(e)
    const float THR = 11.0f;                         // defer-max threshold (log2)

    for (;;) {
        if (t == 0) s_item = atomicAdd(ctr, 1);
        __syncthreads();
        int item = s_item;
        __syncthreads();
        if (item >= NITEMS) return;

        int qt = (NQT - 1) - (item >> 6);   // long q-tiles first
        int h = (item >> 2) & 15;
        int c = item & 3;

        int kmaxf = kv_end[qt * QBLK + QBLK - 1];   // ids sorted -> monotone bound
        int jstart = c * CHUNK;
        if (jstart >= kmaxf) continue;
        int jend = min(jstart + CHUNK, kmaxf);
        int nch = (kmaxf + CHUNK - 1) / CHUNK;

        int qrow = qt * QBLK + w * 32 + lq;
        const __hip_bfloat16* qh = qg + ((size_t)h * NTOK + qrow) * HD;
        bf16x8 qa[4];
        #pragma unroll
        for (int s = 0; s < 4; s++)
            qa[s] = *(const bf16x8*)(qh + hi * 8 + s * 16);

        int ke = kv_end[qrow];                            // bound for q (lane-local)
        int ke0 = kv_end[qt * QBLK + w * 32];             // min bound in wave
        int wave_kemax = kv_end[qt * QBLK + w * 32 + 31]; // wave activity bound

        float m = -1e30f, l = 0.f;                        // lane-partial over hi halves
        f32x16 acc_ot[2] = {};                            // O^T: row d, col q=lq

        // prefetch first tile
        const __hip_bfloat16* kh = kg + ((size_t)h * NTOK + jstart + skey) * HD;
        const __hip_bfloat16* vh = vg + ((size_t)h * NTOK + jstart + skey) * HD;
        bf16x8 kr0 = *(const bf16x8*)(kh + sc0);
        bf16x8 kr1 = *(const bf16x8*)(kh + sc0 + 8);
        bf16x8 vr0 = *(const bf16x8*)(vh + sc0);
        bf16x8 vr1 = *(const bf16x8*)(vh + sc0 + 8);

        for (int jt = jstart; jt < jend; jt += 64) {
            // ---- stage regs -> LDS ----
            int kswz = (skey & 7) << 4;
            *(bf16x8*)(KsB + skey * 128 + ((sc0 * 2) ^ kswz)) = kr0;
            *(bf16x8*)(KsB + skey * 128 + ((sc0 * 2 + 16) ^ kswz)) = kr1;
            int vsega = (((sc0 >> 4) & 3) << 5);
            #pragma unroll
            for (int j = 0; j < 8; j++) {
                int r0 = sc0 + j, r1 = sc0 + 8 + j;
                *(short*)(VtB + r0 * 128 + ((skey * 2) ^ (((r0 & 7) << 4) ^ vsega))) = vr0[j];
                *(short*)(VtB + r1 * 128 + ((skey * 2) ^ (((r1 & 7) << 4) ^ vsega))) = vr1[j];
            }
            __syncthreads();

            // ---- prefetch next tile ----
            if (jt + 64 < jend) {
                const __hip_bfloat16* kh2 = kg + ((size_t)h * NTOK + jt + 64 + skey) * HD;
                const __hip_bfloat16* vh2 = vg + ((size_t)h * NTOK + jt + 64 + skey) * HD;
                kr0 = *(const bf16x8*)(kh2 + sc0);
                kr1 = *(const bf16x8*)(kh2 + sc0 + 8);
                vr0 = *(const bf16x8*)(vh2 + sc0);
                vr1 = *(const bf16x8*)(vh2 + sc0 + 8);
            }

            if (wave_kemax > jt) {   // wave-uniform: skip fully-masked waves
                // ---- S^T = K Q^T : two 32x32 blocks (keys kb*32..+31) ----
                f32x16 sacc[2] = {};
                __builtin_amdgcn_s_setprio(1);
                #pragma unroll
                for (int kb = 0; kb < 2; kb++) {
                    int key = lq + 32 * kb;
                    int ksw = (key & 7) << 4;
                    #pragma unroll
                    for (int s = 0; s < 4; s++) {
                        bf16x8 kf = *(const bf16x8*)(KsB + key * 128 + ((hi * 16 + 32 * s) ^ ksw));
                        sacc[kb] = __builtin_amdgcn_mfma_f32_32x32x16_bf16(kf, qa[s], sacc[kb], 0, 0, 0);
                    }
                }
                __builtin_amdgcn_s_setprio(0);

                // ---- mask RAW scores in place (boundary tiles only) ----
                if (jt + 64 > ke0) {
                    #pragma unroll
                    for (int kb = 0; kb < 2; kb++)
                        #pragma unroll
                        for (int r = 0; r < 16; r++) {
                            int j = jt + 32 * kb + (r & 3) + 8 * (r >> 2) + 4 * hi;
                            if (j >= ke) sacc[kb][r] = -1e30f;
                        }
                }

                // ---- max via max3 tree on raw scores; single scale ----
                float a0  = MAX3(sacc[0][0],  sacc[0][1],  sacc[0][2]);
                float a1  = MAX3(sacc[0][3],  sacc[0][4],  sacc[0][5]);
                float a2  = MAX3(sacc[0][6],  sacc[0][7],  sacc[0][8]);
                float a3  = MAX3(sacc[0][9],  sacc[0][10], sacc[0][11]);
                float a4  = MAX3(sacc[0][12], sacc[0][13], sacc[0][14]);
                float a5  = MAX3(sacc[0][15], sacc[1][0],  sacc[1][1]);
                float a6  = MAX3(sacc[1][2],  sacc[1][3],  sacc[1][4]);
                float a7  = MAX3(sacc[1][5],  sacc[1][6],  sacc[1][7]);
                float a8  = MAX3(sacc[1][8],  sacc[1][9],  sacc[1][10]);
                float a9  = MAX3(sacc[1][11], sacc[1][12], sacc[1][13]);
                float a10 = fmaxf(sacc[1][14], sacc[1][15]);
                float b0 = MAX3(a0, a1, a2);
                float b1 = MAX3(a3, a4, a5);
                float b2 = MAX3(a6, a7, a8);
                float b3 = MAX3(a9, a10, b0);
                float mx = MAX3(b1, b2, b3) * SC;
                mx = fmaxf(mx, __shfl_xor(mx, 32));
                // Clamp: valid scores give mx >= -739; all-masked lanes get -1e9
                // so mn can never equal the sentinel*SC (no fma-residual inf).
                mx = fmaxf(mx, -1e9f);

                float p[2][16];
                if (__all(mx <= m + THR)) {
                    // defer-max: keep old m; exp2(fma(raw, SC, -m))
                    float nm = -m;
                    float l0 = 0.f, l1 = 0.f, l2 = 0.f, l3 = 0.f;
                    #pragma unroll
                    for (int kb = 0; kb < 2; kb++)
                        #pragma unroll
                        for (int r = 0; r < 16; r++) {
                            float e = exp2f(fmaf(sacc[kb][r], SC, nm));
                            p[kb][r] = e;
                            if ((r & 3) == 0) l0 += e;
                            else if ((r & 3) == 1) l1 += e;
                            else if ((r & 3) == 2) l2 += e;
                            else l3 += e;
                        }
                    l += (l0 + l1) + (l2 + l3);
                } else {
                    float mn = fmaxf(m, mx);
                    float al = exp2f(m - mn);
                    l *= al;
                    float nm = -mn;
                    float l0 = 0.f, l1 = 0.f, l2 = 0.f, l3 = 0.f;
                    #pragma unroll
                    for (int kb = 0; kb < 2; kb++)
                        #pragma unroll
                        for (int r = 0; r < 16; r++) {
                            float e = exp2f(fmaf(sacc[kb][r], SC, nm));
                            p[kb][r] = e;
                            if ((r & 3) == 0) l0 += e;
                            else if ((r & 3) == 1) l1 += e;
                            else if ((r & 3) == 2) l2 += e;
                            else l3 += e;
                        }
                    l += (l0 + l1) + (l2 + l3);
                    m = mn;
                    #pragma unroll
                    for (int db = 0; db < 2; db++)
                        #pragma unroll
                        for (int r = 0; r < 16; r++) acc_ot[db][r] *= al;   // al lane-local (q=lq)
                }

                // ---- pack P pairs; permlane32_swap -> PV B-frags in place ----
                uint pw[2][8];
                #pragma unroll
                for (int kb = 0; kb < 2; kb++)
                    #pragma unroll
                    for (int i = 0; i < 8; i++) {
                        union { __hip_bfloat16 b[2]; uint u; } cv;
                        cv.b[0] = __float2bfloat16(p[kb][2 * i]);
                        cv.b[1] = __float2bfloat16(p[kb][2 * i + 1]);
                        pw[kb][i] = cv.u;
                    }
                #pragma unroll
                for (int kb = 0; kb < 2; kb++) {
                    PLSWAP(pw[kb][0], pw[kb][2]);
                    PLSWAP(pw[kb][1], pw[kb][3]);
                    PLSWAP(pw[kb][4], pw[kb][6]);
                    PLSWAP(pw[kb][5], pw[kb][7]);
                }

                // ---- O^T += V^T P^T : D[d][q], col q = lq ----
                __builtin_amdgcn_s_setprio(1);
                #pragma unroll
                for (int db = 0; db < 2; db++) {
                    int d = lq + 32 * db;
                    int vsw = ((d & 7) << 4) ^ (((d >> 4) & 3) << 5);
                    #pragma unroll
                    for (int kb = 0; kb < 2; kb++)
                        #pragma unroll
                        for (int s = 0; s < 2; s++) {
                            bf16x8 vf = *(const bf16x8*)(VtB + d * 128 + ((hi * 16 + 32 * s + 64 * kb) ^ vsw));
                            union { uint u[4]; bf16x8 v; } pf;
                            pf.u[0] = pw[kb][4 * s + 0];
                            pf.u[1] = pw[kb][4 * s + 1];
                            pf.u[2] = pw[kb][4 * s + 2];
                            pf.u[3] = pw[kb][4 * s + 3];
                            acc_ot[db] = __builtin_amdgcn_mfma_f32_32x32x16_bf16(vf, pf.v, acc_ot[db], 0, 0, 0);
                        }
                }
                __builtin_amdgcn_s_setprio(0);
            }
            __syncthreads();
        }

        // reduce lane-partial l across hi halves (q = lq both)
        l += __shfl_xor(l, 32);

        if (nch == 1) {
            float lr = 1.0f / l;   // lane-local
            #pragma unroll
            for (int db = 0; db < 2; db++)
                #pragma unroll
                for (int i = 0; i < 8; i++) {
                    int dl = (2 * i & 3) + 8 * ((2 * i) >> 2) + 4 * hi;   // d_local of reg 2i
                    union { __hip_bfloat16 b[2]; uint u; } cv;
                    cv.b[0] = __float2bfloat16(acc_ot[db][2 * i] * lr);
                    cv.b[1] = __float2bfloat16(acc_ot[db][2 * i + 1] * lr);
                    *(uint*)(ao + (size_t)qrow * DIM + h * 64 + db * 32 + dl) = cv.u;
                }
        } else {
            // opart layout [item][d=64][q=128]: coalesced (q contiguous per d)
            size_t ob = ((size_t)(c * NQT + qt) * HEADS + h) * (64 * QBLK);
            int qloc = w * 32 + lq;
            #pragma unroll
            for (int db = 0; db < 2; db++)
                #pragma unroll
                for (int r = 0; r < 16; r++) {
                    int dl = (r & 3) + 8 * (r >> 2) + 4 * hi + 32 * db;
                    opart[ob + (size_t)dl * QBLK + qloc] = acc_ot[db][r];
                }
            if (hi == 0) {
                size_t mb = ((size_t)(c * NQT + qt) * HEADS + h) * (2 * QBLK);
                mlpart[mb + qloc] = m;
                mlpart[mb + QBLK + qloc] = l;
            }
        }
    }
}

// ---------------- merge split-K partials (opart [d][q]; LDS-transposed writes) ----
__global__ __launch_bounds__(256) void k_merge(const int* __restrict__ kv_end,
                                               const float* __restrict__ opart,
                                               const float* __restrict__ mlpart,
                                               __hip_bfloat16* __restrict__ ao) {
    int qt = blockIdx.x, h = blockIdx.y;
    int kmaxf = kv_end[qt * QBLK + QBLK - 1];
    int nch = (kmaxf + CHUNK - 1) / CHUNK;
    if (nch == 1) return;                    // k_attn wrote ao directly
    __shared__ float os[64][QBLK + 4];       // [d][q], +4 pad
    int t = threadIdx.x;
    int qq = (t & 31) * 4;                   // 4 consecutive q (phase 1)
    int dsub = t >> 5;                       // 0..7

    // per-q merge weights for qq..qq+3
    float4 wc4[NCH];
    float4 inv4;
    {
        float4 mc[NCH], lc[NCH];
        float4 mstar = {-1e30f, -1e30f, -1e30f, -1e30f};
        for (int c = 0; c < nch; c++) {
            size_t mb = ((size_t)(c * NQT + qt) * HEADS + h) * (2 * QBLK);
            mc[c] = *(const float4*)(mlpart + mb + qq);
            lc[c] = *(const float4*)(mlpart + mb + QBLK + qq);
            mstar.x = fmaxf(mstar.x, mc[c].x); mstar.y = fmaxf(mstar.y, mc[c].y);
            mstar.z = fmaxf(mstar.z, mc[c].z); mstar.w = fmaxf(mstar.w, mc[c].w);
        }
        float4 lsum = {0.f, 0.f, 0.f, 0.f};
        for (int c = 0; c < nch; c++) {
            wc4[c].x = exp2f(mc[c].x - mstar.x); wc4[c].y = exp2f(mc[c].y - mstar.y);
            wc4[c].z = exp2f(mc[c].z - mstar.z); wc4[c].w = exp2f(mc[c].w - mstar.w);
            lsum.x += lc[c].x * wc4[c].x; lsum.y += lc[c].y * wc4[c].y;
            lsum.z += lc[c].z * wc4[c].z; lsum.w += lc[c].w * wc4[c].w;
        }
        inv4.x = 1.0f / lsum.x; inv4.y = 1.0f / lsum.y;
        inv4.z = 1.0f / lsum.z; inv4.w = 1.0f / lsum.w;
    }

    // phase 1: coalesced opart reads -> weighted sum -> LDS [d][q]
    #pragma unroll
    for (int iter = 0; iter < 8; iter++) {
        int d = iter * 8 + dsub;
        float4 acc = {0.f, 0.f, 0.f, 0.f};
        for (int c = 0; c < nch; c++) {
            const float4 v = *(const float4*)(opart +
                ((size_t)(c * NQT + qt) * HEADS + h) * (64 * QBLK) + (size_t)d * QBLK + qq);
            acc.x += v.x * wc4[c].x; acc.y += v.y * wc4[c].y;
            acc.z += v.z * wc4[c].z; acc.w += v.w * wc4[c].w;
        }
        acc.x *= inv4.x; acc.y *= inv4.y; acc.z *= inv4.z; acc.w *= inv4.w;
        os[d][qq + 0] = acc.x; os[d][qq + 1] = acc.y;
        os[d][qq + 2] = acc.z; os[d][qq + 3] = acc.w;
    }
    __syncthreads();

    // phase 2: transpose out of LDS; 64B contiguous global write per thread
    int q = t >> 1, d0 = (t & 1) * 32;
    uint buf[16];
    #pragma unroll
    for (int j = 0; j < 16; j++) {
        union { __hip_bfloat16 b[2]; uint u; } cv;
        cv.b[0] = __float2bfloat16(os[d0 + 2 * j][q]);
        cv.b[1] = __float2bfloat16(os[d0 + 2 * j + 1][q]);
        buf[j] = cv.u;
    }
    uint4* dst = (uint4*)(ao + (size_t)(qt * QBLK + q) * DIM + h * 64 + d0);
    dst[0] = make_uint4(buf[0], buf[1], buf[2], buf[3]);
    dst[1] = make_uint4(buf[4], buf[5], buf[6], buf[7]);
    dst[2] = make_uint4(buf[8], buf[9], buf[10], buf[11]);
    dst[3] = make_uint4(buf[12], buf[13], buf[14], buf[15]);
}

extern "C" void kernel_launch(void* const* d_in, const int* in_sizes, int n_in,
                              void* d_out, int out_size, void* d_ws, size_t ws_size,
                              hipStream_t stream) {
    const float* emb   = (const float*)d_in[0];
    const float* normw = (const float*)d_in[1];
    const float* Wq    = (const float*)d_in[2];
    const float* Wk    = (const float*)d_in[3];
    const float* Wv    = (const float*)d_in[4];
    const float* Wo    = (const float*)d_in[5];
    const int*   gidx  = (const int*)d_in[7];
    const int*   sids  = (const int*)d_in[8];
    float* out = (float*)d_out;

    const size_t M4 = (size_t)NTOK * DIM;
    const size_t M1 = (size_t)DIM * DIM;
    __hip_bfloat16* xnb = (__hip_bfloat16*)d_ws;             // 4M
    __hip_bfloat16* wqb = xnb + M4;                          // 1M x4
    __hip_bfloat16* wkb = wqb + M1;
    __hip_bfloat16* wvb = wkb + M1;
    __hip_bfloat16* wob = wvb + M1;
    __hip_bfloat16* qb  = wob + M1;                          // 4M x3
    __hip_bfloat16* kb  = qb + M4;
    __hip_bfloat16* vb  = kb + M4;
    __hip_bfloat16* aob = vb + M4;                           // 4M
    float* sint = (float*)(aob + M4);                        // [4096][32]
    float* cost = sint + (size_t)NTOK * 32;
    int*   kvend = (int*)(cost + (size_t)NTOK * 32);         // [4096]
    float* opart = (float*)(kvend + NTOK);                   // [4][32][16][64*128] f32 = 64MB
    float* mlpart = opart + (size_t)NCH * NQT * HEADS * (64 * QBLK);  // [4][32][16][2*128] f32
    int*   wctr = (int*)(mlpart + (size_t)NCH * NQT * HEADS * (2 * QBLK));

    hipLaunchKernelGGL(k_prologue, dim3(NTOK), dim3(256), 0, stream,
                       emb, normw, Wq, Wk, Wv, Wo, sids, gidx,
                       xnb, wqb, wkb, wvb, wob, kvend, sint, cost, wctr);
    hipLaunchKernelGGL(k_qkv, dim3(NTOK / 128, DIM / 128, 3), dim3(256), 0, stream,
                       xnb, wqb, wkb, wvb, sint, cost, qb, kb, vb);
    hipLaunchKernelGGL(k_attn, dim3(NITEMS), dim3(256), 0, stream,
                       qb, kb, vb, kvend, wctr, opart, mlpart, aob);
    hipLaunchKernelGGL(k_merge, dim3(NQT, HEADS), dim3(256), 0, stream,
                       kvend, opart, mlpart, aob);
    hipLaunchKernelGGL(k_wo, dim3(NTOK / 128, DIM / 128), dim3(256), 0, stream,
                       aob, wob, out);
}